// Round 8
// baseline (67.063 us; speedup 1.0000x reference)
//
#include <hip/hip_runtime.h>
#include <math.h>

#ifndef M_PI
#define M_PI 3.14159265358979323846
#endif

#define NPTS 8192
#define KCOMP 64
#define NBIN 150          // bins of width 0.08 over [-6, 6]
#define XMIN -6.0f
#define BINW_INV 12.5f    // 1/0.08
#define NBLK 256          // 1 block per CU -> trivially co-resident
#define NTHR 1024         // 16 waves
#define MAGIC 0x1357BEEFu
// kern = exp(-8192 d^2): underflows to 0.0f for d > 0.112; at d=0.08 it is
// 1.8e-23 (< 1 ulp of the per-point sum). +-1-bin windowing omits only pairs
// with d > 0.08 -> numerically exact vs the f32 reference. Window edges are
// extended to 16B alignment: the <=3 extra elements per side are >=1 full bin
// (0.08) away -> kern <= 2e-23, vanishes in the f32 sum.
//
// Time model (R0-R7 probes): dur = 39.4us ws-poison fill (harness, fixed)
// + ~22us fixed window overhead + kernel. R7 kernel ~= 4.5us; largest item
// is the cross-block reduce tail (~1.5us: RELEASE propagation + poll sleep).
// R8: (1) pack {MAGIC,partial} into ONE 64-bit RELAXED atomic slot (atomicity
// replaces the release/acquire pair); (2) EVERY block redundantly spins,
// reduces, and stores the bitwise-identical result to out[0] -> the
// last-finishing block takes the fast path (others' slots already visible),
// removing cross-block propagation + poll latency from the critical path.

// Single-instruction hardware exp2 (v_exp_f32).
__device__ __forceinline__ float fexp2(float a) {
#if __has_builtin(__builtin_amdgcn_exp2f)
  return __builtin_amdgcn_exp2f(a);
#else
  float r;
  asm("v_exp_f32 %0, %1" : "=v"(r) : "v"(a));
  return r;
#endif
}

__global__ __launch_bounds__(NTHR) void gmm_kernel(
    const float* __restrict__ x,
    const float* __restrict__ logits,
    const float* __restrict__ means,
    const float* __restrict__ log_vars,
    float* __restrict__ ws,
    float* __restrict__ out) {
  __shared__ alignas(16) float xs[NPTS];   // bin-sorted, UNSCALED (32 KB)
  __shared__ int hist[NBIN];
  __shared__ int bst[NBIN + 2];
  __shared__ float sa[KCOMP], sq[KCOMP], smn[KCOMP];
  __shared__ float wsum[16];

  const int t = threadIdx.x;

  // ---- issue ALL global loads up front (one miss round, overlapped) ----
  const float4* x4 = reinterpret_cast<const float4*>(x);
  float4 va = x4[t];           // floats [0, 4096)
  float4 vb = x4[t + NTHR];    // floats [4096, 8192)
  float pl = 0.f, plv = 0.f, pmn = 0.f;
  if (t >= 64 && t < 128) {    // wave 1 fetches softmax params
    pl  = logits[t - 64];
    plv = log_vars[t - 64];
    pmn = means[t - 64];
  }
  if (t < NBIN) hist[t] = 0;
  __syncthreads();                                    // B1

  // ---- phase 1: bin + rank via ONE atomic round ----
  float xv[8] = {va.x, va.y, va.z, va.w, vb.x, vb.y, vb.z, vb.w};
  int bn[8], rk[8];
#pragma unroll
  for (int r = 0; r < 8; ++r) {
    int b = (int)((xv[r] - XMIN) * BINW_INV);
    b = b < 0 ? 0 : (b > NBIN - 1 ? NBIN - 1 : b);
    bn[r] = b;
    rk[r] = atomicAdd(&hist[b], 1);   // return value = within-bin rank
  }
  // wave 1: softmax over K=64 logits + component params (needs only the
  // hoisted loads -> runs before B2, off the scan critical path)
  if (t >= 64 && t < 128) {
    int k = t - 64;
    float m = pl;
#pragma unroll
    for (int off = 32; off > 0; off >>= 1) m = fmaxf(m, __shfl_xor(m, off));
    float e = expf(pl - m);
    float ssum = e;
#pragma unroll
    for (int off = 32; off > 0; off >>= 1) ssum += __shfl_xor(ssum, off);
    float w = e / ssum;
    float var = expf(plv);
    sa[k] = w * rsqrtf(2.0f * (float)M_PI * var);   // amplitude
    sq[k] = 0.72134752044448170368f / var;          // 0.5*log2(e)/var
    smn[k] = pmn;
  }
  __syncthreads();                                    // B2
  if (t < 64) {
    // wave 0: barrier-free shfl scan over 150 bins (3 chunks of 64)
    int h0 = hist[t], h1 = hist[t + 64];
    int h2 = (t < NBIN - 128) ? hist[t + 128] : 0;
    int v0 = h0, v1 = h1, v2 = h2;
#pragma unroll
    for (int off = 1; off < 64; off <<= 1) {
      int a0 = __shfl_up(v0, off);
      int a1 = __shfl_up(v1, off);
      int a2 = __shfl_up(v2, off);
      if (t >= off) { v0 += a0; v1 += a1; v2 += a2; }
    }
    int tot0 = __shfl(v0, 63), tot1 = __shfl(v1, 63);
    bst[t] = v0 - h0;                          // exclusive starts
    bst[t + 64] = tot0 + v1 - h1;
    if (t < NBIN - 128) bst[t + 128] = tot0 + tot1 + v2 - h2;
    if (t == 0) bst[NBIN] = NPTS;
  }
  __syncthreads();                                    // B3
#pragma unroll
  for (int r = 0; r < 8; ++r)
    xs[bst[bn[r]] + rk[r]] = xv[r];   // scatter: no second atomic round
  __syncthreads();                                    // B4

  // ---- phase 2: windowed KDE (b128 reads) + mixture + MSE ----
  const float inv_norm = 1.0f / (2.50662827463100050242f * 64.0f);
  const float C = 8192.0f * 1.44269504088896340736f;  // 8192*log2(e)
  const int lane = t & 63;
  const int wv = t >> 6;
  const int gw = blockIdx.x * 16 + wv;   // 4096 waves, 2 sorted positions each
  const float sal = sa[lane], sql = sq[lane], sml = smn[lane];
  const float4* xs4 = reinterpret_cast<const float4*>(xs);

  float vsum = 0.0f;
#pragma unroll
  for (int r = 0; r < 2; ++r) {
    const int p = gw + r * 4096;     // pair left-half/right-half quantiles
    const float u = xs[p];           // LDS broadcast
    int b = (int)((u - XMIN) * BINW_INV);
    b = b < 0 ? 0 : (b > NBIN - 1 ? NBIN - 1 : b);
    const int q0 = bst[b > 0 ? b - 1 : 0] >> 2;                     // floor/16B
    const int q1 = (bst[(b + 2) > NBIN ? NBIN : (b + 2)] + 3) >> 2; // ceil/16B
    float acc0 = 0.f, acc1 = 0.f;
    for (int q = q0 + lane; q < q1; q += 64) {
      float4 v = xs4[q];             // ds_read_b128, conflict-free
      float d0 = u - v.x, d1 = u - v.y, d2 = u - v.z, d3 = u - v.w;
      acc0 += fexp2(-(C * d0) * d0);
      acc1 += fexp2(-(C * d1) * d1);
      acc0 += fexp2(-(C * d2) * d2);
      acc1 += fexp2(-(C * d3) * d3);
    }
    float acc = acc0 + acc1;
    // mixture: one component per lane
    float dm = u - sml;
    float mixl = sal * fexp2(-(sql * dm) * dm);
    // joint butterfly reduce (all lanes end with the wave sums)
#pragma unroll
    for (int off = 32; off > 0; off >>= 1) {
      acc += __shfl_xor(acc, off);
      mixl += __shfl_xor(mixl, off);
    }
    float diff = mixl - acc * inv_norm;
    vsum += diff * diff;
  }
  if (lane == 0) wsum[wv] = vsum;
  __syncthreads();                                    // B5

  // ---- phase 3: poison-immune cross-block reduction, all-blocks redundant --
  // One packed 64-bit RELAXED atomic per block: {MAGIC:hi32, partial:lo32}.
  // Atomicity delivers flag+value together -> no release/acquire pair needed.
  unsigned long long* slot = reinterpret_cast<unsigned long long*>(ws);
  if (t == 0) {
    float p = 0.f;
#pragma unroll
    for (int i = 0; i < 16; ++i) p += wsum[i];
    unsigned long long pk = ((unsigned long long)MAGIC << 32) |
                            (unsigned long long)__float_as_uint(p);
    __hip_atomic_store(&slot[blockIdx.x], pk, __ATOMIC_RELAXED,
                       __HIP_MEMORY_SCOPE_AGENT);
  }
  if (t < 64) {
    // wave 0 of EVERY block: identical deterministic reduce; all 256 blocks
    // store the same bits to out[0] (benign). Last-finishing block sees all
    // other slots already set -> fast path, no propagation wait.
    float v = 0.f;
#pragma unroll
    for (int k = 0; k < 4; ++k) {
      const int idx = t + k * 64;
      unsigned long long pk;
      while ((unsigned)((pk = __hip_atomic_load(&slot[idx], __ATOMIC_RELAXED,
                                                __HIP_MEMORY_SCOPE_AGENT))
                        >> 32) != MAGIC)
        __builtin_amdgcn_s_sleep(1);
      v += __uint_as_float((unsigned)pk);
    }
#pragma unroll
    for (int off = 32; off > 0; off >>= 1) v += __shfl_xor(v, off);
    if (t == 0) out[0] = v;              // plain store, identical in all blocks
  }
}

extern "C" void kernel_launch(void* const* d_in, const int* in_sizes, int n_in,
                              void* d_out, int out_size, void* d_ws, size_t ws_size,
                              hipStream_t stream) {
  const float* x     = (const float*)d_in[0];
  const float* wl    = (const float*)d_in[1];
  const float* means = (const float*)d_in[2];
  const float* lv    = (const float*)d_in[3];
  float* out = (float*)d_out;
  float* ws  = (float*)d_ws;   // uses 2 KB (256 packed {flag,partial} qwords)

  gmm_kernel<<<NBLK, NTHR, 0, stream>>>(x, wl, means, lv, ws, out);
}